// Round 9
// baseline (11269.553 us; speedup 1.0000x reference)
//
#include <hip/hip_runtime.h>

#define B_ 64
#define S_ 512
#define H_ 512

typedef unsigned short u16;
typedef unsigned int   u32;
typedef unsigned long long u64;

typedef __attribute__((ext_vector_type(8))) short    bf16x8;
typedef __attribute__((ext_vector_type(8))) _Float16 f16x8;
typedef __attribute__((ext_vector_type(4))) float    f32x4;
typedef __attribute__((ext_vector_type(2))) _Float16 h2_t;

#define PJ_GATE ((size_t)512 * 64 * 512)   // P stride per gate: [512 ts][64 b][512 j]

// ---------- helpers ----------
__device__ inline u16 f2bf(float f) {            // RNE fp32 -> bf16 bits
  u32 u = __builtin_bit_cast(u32, f);
  u32 r = (u + 0x7fffu + ((u >> 16) & 1u)) >> 16;
  return (u16)r;
}
__device__ inline u32 pkbf2(float a, float b) {
  return (u32)f2bf(a) | ((u32)f2bf(b) << 16);
}
__device__ inline u16 f2h(float a) {
  _Float16 x = (_Float16)a;
  return __builtin_bit_cast(u16, x);
}
__device__ inline u32 pk2h(float a, float b) {
  return (u32)f2h(a) | ((u32)f2h(b) << 16);
}
__device__ inline float h2f(u16 b) {
  return (float)__builtin_bit_cast(_Float16, b);
}
__device__ inline float sigmoidf_(float x) { return 1.f / (1.f + __expf(-x)); }
__device__ inline float tanhf_(float x) {
  float e = __expf(-2.f * fabsf(x));
  float t = (1.f - e) / (1.f + e);
  return copysignf(t, x);
}
__device__ inline void xstore64(u64* p, u64 v) {
  __hip_atomic_store(p, v, __ATOMIC_RELAXED, __HIP_MEMORY_SCOPE_AGENT);
}
__device__ inline u64 xload(const u64* p) {
  return __hip_atomic_load(p, __ATOMIC_RELAXED, __HIP_MEMORY_SCOPE_AGENT);
}
// u64 = [tag|f16][tag|f16]: low f16 at bits 0..15, high f16 at bits 32..47
__device__ inline float lo16f(u64 v) { return h2f((u16)(v & 0xffffu)); }
__device__ inline float hi16f(u64 v) { return h2f((u16)((v >> 32) & 0xffffu)); }

// ---------- kernel 1: W recurrent half -> f16 MFMA A-fragments ----------
// WF[g][rt][kt][lane] (uint4): 8 f16 = W_g[rt*16+(lane&15)][512 + kt*32 + (lane>>4)*8 + 0..7]
__global__ void k_convert_w(const float* __restrict__ Wr, const float* __restrict__ Wz,
                            const float* __restrict__ Wh, uint4* __restrict__ WF) {
  int g = blockIdx.y;
  const float* Ws = (g == 0) ? Wr : ((g == 1) ? Wz : Wh);
  int i = blockIdx.x * 256 + threadIdx.x;   // 0..32767
  int lane = i & 63;
  int kt   = (i >> 6) & 15;
  int rt   = i >> 10;                       // 0..31
  int row  = rt * 16 + (lane & 15);
  int col  = 512 + kt * 32 + (lane >> 4) * 8;
  const float* src = Ws + (size_t)row * 1024 + col;
  float4 a = *(const float4*)src;
  float4 b = *(const float4*)(src + 4);
  uint4 o;
  o.x = pk2h(a.x, a.y); o.y = pk2h(a.z, a.w);
  o.z = pk2h(b.x, b.y); o.w = pk2h(b.z, b.w);
  WF[((size_t)(g * 32 + rt) * 16 + kt) * 64 + lane] = o;
}

// ---------- kernel 2: projection GEMM (f32 in, bf16 MFMA, f16 out) ----------
__global__ __launch_bounds__(256) void k_proj_gemm(
    const float* __restrict__ x,
    const float* __restrict__ Wr, const float* __restrict__ Wz, const float* __restrict__ Wh,
    const float* __restrict__ br, const float* __restrict__ bz, const float* __restrict__ bh,
    u16* __restrict__ P)
{
  const int g  = blockIdx.z;
  const int bm = blockIdx.x * 64;
  const int bn = blockIdx.y * 64;
  const float* Ws = (g == 0) ? Wr : ((g == 1) ? Wz : Wh);
  __shared__ __align__(16) u16 As[64][32];
  __shared__ __align__(16) u16 Bs[64][32];
  const int tid  = threadIdx.x;
  const int lane = tid & 63;
  const int wm   = (tid >> 6) >> 1;
  const int wn   = (tid >> 6) & 1;
  const int srow = tid >> 2;
  const int scol = (tid & 3) * 8;

  f32x4 zero4 = {0.f, 0.f, 0.f, 0.f};
  f32x4 acc[2][2];
  acc[0][0] = zero4; acc[0][1] = zero4; acc[1][0] = zero4; acc[1][1] = zero4;

  for (int k0 = 0; k0 < 512; k0 += 32) {
    __syncthreads();
    {
      const float* xs = x + (size_t)(bm + srow) * 512 + k0 + scol;
      float4 a = *(const float4*)xs, b = *(const float4*)(xs + 4);
      uint4 av; av.x = pkbf2(a.x, a.y); av.y = pkbf2(a.z, a.w);
      av.z = pkbf2(b.x, b.y); av.w = pkbf2(b.z, b.w);
      *(uint4*)(&As[srow][scol]) = av;
      const float* wsrc = Ws + (size_t)(bn + srow) * 1024 + k0 + scol;
      float4 c = *(const float4*)wsrc, d = *(const float4*)(wsrc + 4);
      uint4 bv; bv.x = pkbf2(c.x, c.y); bv.y = pkbf2(c.z, c.w);
      bv.z = pkbf2(d.x, d.y); bv.w = pkbf2(d.z, d.w);
      *(uint4*)(&Bs[srow][scol]) = bv;
    }
    __syncthreads();
#pragma unroll
    for (int mi = 0; mi < 2; ++mi) {
      bf16x8 a = *(const bf16x8*)(&As[wm * 32 + mi * 16 + (lane & 15)][(lane >> 4) * 8]);
#pragma unroll
      for (int ni = 0; ni < 2; ++ni) {
        bf16x8 b = *(const bf16x8*)(&Bs[wn * 32 + ni * 16 + (lane & 15)][(lane >> 4) * 8]);
        acc[mi][ni] = __builtin_amdgcn_mfma_f32_16x16x32_bf16(a, b, acc[mi][ni], 0, 0, 0);
      }
    }
  }
  const float* bias = (g == 0) ? br : ((g == 1) ? bz : bh);
#pragma unroll
  for (int mi = 0; mi < 2; ++mi)
#pragma unroll
    for (int ni = 0; ni < 2; ++ni) {
      int col  = bn + wn * 32 + ni * 16 + (lane & 15);
      float bv = bias[col];
#pragma unroll
      for (int r = 0; r < 4; ++r) {
        int row = bm + wm * 32 + mi * 16 + (lane >> 4) * 4 + r;
        int bb = row >> 9, ss = row & 511;
        float v = acc[mi][ni][r] + bv;
        P[((size_t)g * 512 + ss) * (64 * 512) + (size_t)bb * 512 + col] =
            __builtin_bit_cast(u16, (_Float16)v);
      }
    }
}

// ---------- kernel 3: GRU scan — one LLC round-trip per step ----------
// 16 blocks x 512 thr, 1 block/CU (launch_bounds(512,1) -> 256-VGPR cap).
// cluster c = blockIdx>>2 owns batches 16c..16c+15; block q = blockIdx&3:
//   phase A (row-split): rows [128q,128q+128) of W_r,W_z in VGPRs -> r,z.
//     rh for k-slice [128q,128q+128) is LOCAL (own rows). Publish z (tagged).
//   phase B (k-split): W_h[:, own 128 k] in LDS -> f16 partial htilde for ALL
//     512 j. Publish tagged partials.
//   ONE bulk tag-poll (4x partials + z), then every block combines redundantly:
//     h carried in f32 regs per combine-thread; f16 h written to LDS hbuf.
__global__ __launch_bounds__(512, 1) void k_gru_scan(
    const float* __restrict__ h0,
    const u16*  __restrict__ P,       // [3][512 ts][64 b][512 j] f16
    const uint4* __restrict__ WF,     // fragment-packed recurrent W (f16)
    u32* __restrict__ PX,             // [2 par][4 c][4 q][16 b][512 j] tagged partials
    u32* __restrict__ ZX,             // [2 par][4 c][16 b][512 j] tagged z
    float* __restrict__ y,
    float* __restrict__ hlast)
{
  const int q = blockIdx.x & 3;
  const int c = blockIdx.x >> 2;
  const int t = threadIdx.x;
  const int w = t >> 6;          // wave 0..7
  const int l = t & 63;
  const int bq = l & 15;         // batch within cluster (MFMA mapping)
  const int g4 = l >> 4;         // 0..3
  const int bgA = c * 16 + bq;
  const int j0A = q * 128 + w * 16 + g4 * 4;   // own rows (4)
  const int kloc = w * 16 + g4 * 4;            // = j0A - q*128

  // combine mapping: thread covers (bC, j0C..j0C+15)
  const int bC  = t >> 5;                      // 0..15
  const int j0C = (t & 31) * 16;               // 0..496
  const int bgC = c * 16 + bC;
  const bool ownC = ((j0C >> 7) == q);

  __shared__ __align__(16) u16 whlds[32 * 4 * 64 * 8];  // 128 KB [jt][kk][lane][8]
  __shared__ __align__(16) u16 hbuf[16 * 520];          // f16 h [b][j] (pad 8)
  __shared__ __align__(16) u16 rhs[16 * 136];           // f16 r*h [b][k_local] (pad 8)

  // --- W_r/W_z fragments (own rows) into VGPRs; W_h k-slice into LDS ---
  const int rt = q * 8 + w;
  f16x8 wr[16], wz[16];
#pragma unroll
  for (int kt = 0; kt < 16; ++kt) {
    wr[kt] = __builtin_bit_cast(f16x8, WF[((size_t)(0 * 32 + rt) * 16 + kt) * 64 + l]);
    wz[kt] = __builtin_bit_cast(f16x8, WF[((size_t)(1 * 32 + rt) * 16 + kt) * 64 + l]);
  }
#pragma unroll
  for (int it = 0; it < 16; ++it) {
    int i = it * 512 + t;                  // 0..8191
    int jt = i >> 8, kk = (i >> 6) & 3, ln = i & 63;
    uint4 v = WF[((size_t)(2 * 32 + jt) * 16 + (q * 4 + kk)) * 64 + ln];
    *(uint4*)&whlds[((jt * 4 + kk) * 64 + ln) * 8] = v;
  }
#pragma unroll
  for (int kt = 0; kt < 16; ++kt)
    asm volatile("" : "+v"(wr[kt]), "+v"(wz[kt]));   // pin against remat

  // --- init h: f32 regs (combine mapping) + f16 hbuf ---
  f32x4 hold4[4];
#pragma unroll
  for (int v = 0; v < 4; ++v)
    hold4[v] = *(const f32x4*)(h0 + (size_t)bgC * 512 + j0C + v * 4);
  {
    u32 hu[8];
#pragma unroll
    for (int i = 0; i < 8; ++i)
      hu[i] = pk2h(hold4[i >> 1][(i & 1) * 2], hold4[i >> 1][(i & 1) * 2 + 1]);
    uint4 a = {hu[0], hu[1], hu[2], hu[3]};
    uint4 b = {hu[4], hu[5], hu[6], hu[7]};
    *(uint4*)&hbuf[bC * 520 + j0C] = a;
    *(uint4*)&hbuf[bC * 520 + j0C + 8] = b;
  }
  __syncthreads();

  const u16* Ppr = P + (size_t)bgA * 512 + j0A;
  const u16* Ppz = P + PJ_GATE + (size_t)bgA * 512 + j0A;
  const u16* PphC = P + 2 * PJ_GATE + (size_t)bgC * 512 + j0C;

  const int PXCL = 4 * 16 * 512;   // u32 per cluster
  const int PXPAR = 4 * PXCL;
  const int ZXCL = 16 * 512;
  const int ZXPAR = 4 * ZXCL;
  const u64 TMASK = 0xffff0000ffff0000ull;

  uint2 pru = *(const uint2*)Ppr;
  uint2 pzu = *(const uint2*)Ppz;

  for (int ts = 0; ts < S_; ++ts) {
    const int par = ts & 1;
    const u32 taghi = (u32)(ts + 1) << 16;
    const u64 tp = (u64)taghi | ((u64)taghi << 32);
    u32* PXp = PX + par * PXPAR + c * PXCL;
    u32* ZXp = ZX + par * ZXPAR + c * ZXCL;

    // prefetch P_h for combine (combine mapping)
    uint4 pha = *(const uint4*)(PphC + (size_t)ts * 32768);
    uint4 phb = *(const uint4*)(PphC + (size_t)ts * 32768 + 8);

    // ---- phase A: r,z = sigmoid(W_rz · h + P_rz), own 128 rows ----
    f32x4 ar = {0.f, 0.f, 0.f, 0.f}, az = {0.f, 0.f, 0.f, 0.f};
#pragma unroll
    for (int kt = 0; kt < 16; ++kt) {
      f16x8 hv = *(const f16x8*)&hbuf[bq * 520 + g4 * 8 + kt * 32];
      ar = __builtin_amdgcn_mfma_f32_16x16x32_f16(wr[kt], hv, ar, 0, 0, 0);
      az = __builtin_amdgcn_mfma_f32_16x16x32_f16(wz[kt], hv, az, 0, 0, 0);
    }
    h2_t pr0 = __builtin_bit_cast(h2_t, pru.x), pr1 = __builtin_bit_cast(h2_t, pru.y);
    h2_t pz0 = __builtin_bit_cast(h2_t, pzu.x), pz1 = __builtin_bit_cast(h2_t, pzu.y);
    float rr0 = sigmoidf_(ar[0] + (float)pr0[0]);
    float rr1 = sigmoidf_(ar[1] + (float)pr0[1]);
    float rr2 = sigmoidf_(ar[2] + (float)pr1[0]);
    float rr3 = sigmoidf_(ar[3] + (float)pr1[1]);
    float zz0 = sigmoidf_(az[0] + (float)pz0[0]);
    float zz1 = sigmoidf_(az[1] + (float)pz0[1]);
    float zz2 = sigmoidf_(az[2] + (float)pz1[0]);
    float zz3 = sigmoidf_(az[3] + (float)pz1[1]);
    // publish z (tagged) ASAP
    {
      u64 a = (u64)(taghi | f2h(zz0)) | ((u64)(taghi | f2h(zz1)) << 32);
      u64 b = (u64)(taghi | f2h(zz2)) | ((u64)(taghi | f2h(zz3)) << 32);
      xstore64((u64*)(ZXp + bq * 512 + j0A), a);
      xstore64((u64*)(ZXp + bq * 512 + j0A + 2), b);
    }
    // rh for own k-slice (h_old f16 from hbuf, as in round 4)
    {
      uint2 hAp = *(const uint2*)&hbuf[bq * 520 + j0A];
      h2_t hA0 = __builtin_bit_cast(h2_t, hAp.x), hA1 = __builtin_bit_cast(h2_t, hAp.y);
      uint2 rp;
      rp.x = pk2h(rr0 * (float)hA0[0], rr1 * (float)hA0[1]);
      rp.y = pk2h(rr2 * (float)hA1[0], rr3 * (float)hA1[1]);
      *(uint2*)&rhs[bq * 136 + kloc] = rp;
    }
    __syncthreads();   // rhs ready

    // ---- phase B: partial htilde (own k-slice) for ALL 512 j ----
    f32x4 pt0 = {0.f, 0.f, 0.f, 0.f}, pt1 = pt0, pt2 = pt0, pt3 = pt0;
#pragma unroll
    for (int kk = 0; kk < 4; ++kk) {
      f16x8 rv = *(const f16x8*)&rhs[bq * 136 + g4 * 8 + kk * 32];
      f16x8 w0 = *(const f16x8*)&whlds[(((w * 4 + 0) * 4 + kk) * 64 + l) * 8];
      f16x8 w1 = *(const f16x8*)&whlds[(((w * 4 + 1) * 4 + kk) * 64 + l) * 8];
      f16x8 w2 = *(const f16x8*)&whlds[(((w * 4 + 2) * 4 + kk) * 64 + l) * 8];
      f16x8 w3 = *(const f16x8*)&whlds[(((w * 4 + 3) * 4 + kk) * 64 + l) * 8];
      pt0 = __builtin_amdgcn_mfma_f32_16x16x32_f16(w0, rv, pt0, 0, 0, 0);
      pt1 = __builtin_amdgcn_mfma_f32_16x16x32_f16(w1, rv, pt1, 0, 0, 0);
      pt2 = __builtin_amdgcn_mfma_f32_16x16x32_f16(w2, rv, pt2, 0, 0, 0);
      pt3 = __builtin_amdgcn_mfma_f32_16x16x32_f16(w3, rv, pt3, 0, 0, 0);
    }
    // publish tagged f16 partials: PX[q][b][j], j = (4w+ti)*16 + g4*4 + r
    {
      u32* pxme = PXp + ((q * 16 + bq) << 9);
#define PUBT(ti, P4)                                                            \
      {                                                                         \
        int jb = (4 * w + ti) * 16 + g4 * 4;                                    \
        u64 a = (u64)(taghi | f2h(P4[0])) | ((u64)(taghi | f2h(P4[1])) << 32);  \
        u64 b = (u64)(taghi | f2h(P4[2])) | ((u64)(taghi | f2h(P4[3])) << 32);  \
        xstore64((u64*)(pxme + jb), a);                                         \
        xstore64((u64*)(pxme + jb + 2), b);                                     \
      }
      PUBT(0, pt0) PUBT(1, pt1) PUBT(2, pt2) PUBT(3, pt3)
#undef PUBT
    }
    // prefetch next step's P_r/P_z (overlaps poll)
    {
      int tsn = (ts < S_ - 1) ? ts + 1 : ts;
      pru = *(const uint2*)(Ppr + (size_t)tsn * 32768);
      pzu = *(const uint2*)(Ppz + (size_t)tsn * 32768);
    }

    // ---- ONE bulk tag-poll: 4x partials + z for (bC, j0C..+15) ----
    u64 pv0[8], pv1[8], pv2[8], pv3[8], zv[8];
    {
      const u64* b0 = (const u64*)(PXp + ((0 * 16 + bC) << 9) + j0C);
      const u64* b1 = (const u64*)(PXp + ((1 * 16 + bC) << 9) + j0C);
      const u64* b2 = (const u64*)(PXp + ((2 * 16 + bC) << 9) + j0C);
      const u64* b3 = (const u64*)(PXp + ((3 * 16 + bC) << 9) + j0C);
      const u64* bz_ = (const u64*)(ZXp + (bC << 9) + j0C);
#pragma unroll
      for (int i = 0; i < 8; ++i) pv0[i] = xload(b0 + i);
#pragma unroll
      for (int i = 0; i < 8; ++i) pv1[i] = xload(b1 + i);
#pragma unroll
      for (int i = 0; i < 8; ++i) pv2[i] = xload(b2 + i);
#pragma unroll
      for (int i = 0; i < 8; ++i) pv3[i] = xload(b3 + i);
#pragma unroll
      for (int i = 0; i < 8; ++i) zv[i] = xload(bz_ + i);
#pragma unroll
      for (int i = 0; i < 8; ++i)
        while ((pv0[i] ^ tp) & TMASK) { __builtin_amdgcn_s_sleep(1); pv0[i] = xload(b0 + i); }
#pragma unroll
      for (int i = 0; i < 8; ++i)
        while ((pv1[i] ^ tp) & TMASK) { __builtin_amdgcn_s_sleep(1); pv1[i] = xload(b1 + i); }
#pragma unroll
      for (int i = 0; i < 8; ++i)
        while ((pv2[i] ^ tp) & TMASK) { __builtin_amdgcn_s_sleep(1); pv2[i] = xload(b2 + i); }
#pragma unroll
      for (int i = 0; i < 8; ++i)
        while ((pv3[i] ^ tp) & TMASK) { __builtin_amdgcn_s_sleep(1); pv3[i] = xload(b3 + i); }
#pragma unroll
      for (int i = 0; i < 8; ++i)
        while ((zv[i] ^ tp) & TMASK) { __builtin_amdgcn_s_sleep(1); zv[i] = xload(bz_ + i); }
    }

    // ---- combine (redundant, all j of (bC, j0C..+15)) ----
    {
      u32 phw[8];
      phw[0] = pha.x; phw[1] = pha.y; phw[2] = pha.z; phw[3] = pha.w;
      phw[4] = phb.x; phw[5] = phb.y; phw[6] = phb.z; phw[7] = phb.w;
      u32 hu[8];
#pragma unroll
      for (int i = 0; i < 16; ++i) {
        const int k = i >> 1;
        float s, zf, pf;
        if (i & 1) {
          s  = hi16f(pv0[k]) + hi16f(pv1[k]) + hi16f(pv2[k]) + hi16f(pv3[k]);
          zf = hi16f(zv[k]);
          pf = h2f((u16)(phw[k] >> 16));
        } else {
          s  = lo16f(pv0[k]) + lo16f(pv1[k]) + lo16f(pv2[k]) + lo16f(pv3[k]);
          zf = lo16f(zv[k]);
          pf = h2f((u16)(phw[k] & 0xffffu));
        }
        float ho = hold4[i >> 2][i & 3];
        float ht = tanhf_(s + pf);
        float hn = zf * ht + (1.f - zf) * ho;
        hold4[i >> 2][i & 3] = hn;
        u16 hb = f2h(hn);
        if (i & 1) hu[k] |= ((u32)hb << 16);
        else       hu[k] = (u32)hb;
      }
      uint4 a = {hu[0], hu[1], hu[2], hu[3]};
      uint4 b = {hu[4], hu[5], hu[6], hu[7]};
      *(uint4*)&hbuf[bC * 520 + j0C] = a;
      *(uint4*)&hbuf[bC * 520 + j0C + 8] = b;
      if (ownC) {
        float* yp = y + ((size_t)bgC * 512 + ts) * 512 + j0C;
#pragma unroll
        for (int v = 0; v < 4; ++v)
          __builtin_nontemporal_store(hold4[v], (f32x4*)(yp + v * 4));
      }
    }
    __syncthreads();   // hbuf complete for next phase A
  }

  if (ownC) {
#pragma unroll
    for (int v = 0; v < 4; ++v)
      *(f32x4*)(hlast + (size_t)bgC * 512 + j0C + v * 4) = hold4[v];
  }
}

// ---------- host ----------
extern "C" void kernel_launch(void* const* d_in, const int* in_sizes, int n_in,
                              void* d_out, int out_size, void* d_ws, size_t ws_size,
                              hipStream_t stream) {
  const float* x  = (const float*)d_in[0];
  const float* h0 = (const float*)d_in[1];
  const float* Wr = (const float*)d_in[2];
  const float* br = (const float*)d_in[3];
  const float* Wz = (const float*)d_in[4];
  const float* bz = (const float*)d_in[5];
  const float* Wh = (const float*)d_in[6];
  const float* bh = (const float*)d_in[7];

  char* ws = (char*)d_ws;
  // layout: WF 1.5MB @0 | P 96MB @2MB | PX 1MB @102760448 | ZX 256KB
  uint4* WF = (uint4*)ws;
  u16*   P  = (u16*)(ws + 2097152);
  u32*   PX = (u32*)(ws + 102760448);
  u32*   ZX = (u32*)(ws + 103809024);

  float* y     = (float*)d_out;
  float* hlast = y + (size_t)B_ * S_ * H_;

  (void)hipMemsetAsync(ws + 102760448, 0, 1310720, stream);   // clear exchange tags
  k_convert_w<<<dim3(128, 3), dim3(256), 0, stream>>>(Wr, Wz, Wh, WF);
  k_proj_gemm<<<dim3(512, 8, 3), dim3(256), 0, stream>>>(x, Wr, Wz, Wh, br, bz, bh, P);
  k_gru_scan<<<dim3(16), dim3(512), 0, stream>>>(h0, P, WF, PX, ZX, y, hlast);
}

// Round 10
// 5271.980 us; speedup vs baseline: 2.1376x; 2.1376x over previous
//
#include <hip/hip_runtime.h>

#define B_ 64
#define S_ 512
#define H_ 512

typedef unsigned short u16;
typedef unsigned int   u32;
typedef unsigned long long u64;

typedef __attribute__((ext_vector_type(8))) short    bf16x8;
typedef __attribute__((ext_vector_type(8))) _Float16 f16x8;
typedef __attribute__((ext_vector_type(4))) float    f32x4;
typedef __attribute__((ext_vector_type(2))) _Float16 h2_t;

#define PJ_GATE ((size_t)512 * 64 * 512)   // P stride per gate: [512 ts][64 b][512 j]
#define TMASK 0xffff0000ffff0000ull

// ---------- helpers ----------
__device__ inline u16 f2bf(float f) {            // RNE fp32 -> bf16 bits
  u32 u = __builtin_bit_cast(u32, f);
  u32 r = (u + 0x7fffu + ((u >> 16) & 1u)) >> 16;
  return (u16)r;
}
__device__ inline u32 pkbf2(float a, float b) {
  return (u32)f2bf(a) | ((u32)f2bf(b) << 16);
}
__device__ inline u16 f2h(float a) {
  _Float16 x = (_Float16)a;
  return __builtin_bit_cast(u16, x);
}
__device__ inline u32 pk2h(float a, float b) {
  return (u32)f2h(a) | ((u32)f2h(b) << 16);
}
__device__ inline float sigmoidf_(float x) { return 1.f / (1.f + __expf(-x)); }
__device__ inline float tanhf_(float x) {
  float e = __expf(-2.f * fabsf(x));
  float t = (1.f - e) / (1.f + e);
  return copysignf(t, x);
}
__device__ inline void xstore64(u64* p, u64 v) {
  __hip_atomic_store(p, v, __ATOMIC_RELAXED, __HIP_MEMORY_SCOPE_AGENT);
}
__device__ inline u64 xload(const u64* p) {
  return __hip_atomic_load(p, __ATOMIC_RELAXED, __HIP_MEMORY_SCOPE_AGENT);
}
// publish 4 f32 as tagged f16 u32 slots (2 x u64)
__device__ inline void pub4(u32* gp, u32 taghi, f32x4 v) {
  u64 a = (u64)(taghi | f2h(v[0])) | ((u64)(taghi | f2h(v[1])) << 32);
  u64 b = (u64)(taghi | f2h(v[2])) | ((u64)(taghi | f2h(v[3])) << 32);
  xstore64((u64*)gp, a);
  xstore64((u64*)(gp + 2), b);
}
// poll 8 contiguous u64 tagged slots; pack 16 f16 into LDS (2 x uint4)
__device__ inline void poll8_to_lds(const u32* gbase, u16* lbase, u64 tp) {
  const u64* p = (const u64*)gbase;
  u64 v[8];
#pragma unroll
  for (int i = 0; i < 8; ++i) v[i] = xload(p + i);
#pragma unroll
  for (int i = 0; i < 8; ++i)
    while ((v[i] ^ tp) & TMASK) { __builtin_amdgcn_s_sleep(1); v[i] = xload(p + i); }
  u32 pk[8];
#pragma unroll
  for (int i = 0; i < 8; ++i)
    pk[i] = (u32)(v[i] & 0xffffu) | (((u32)(v[i] >> 32)) << 16);
  uint4 a = {pk[0], pk[1], pk[2], pk[3]};
  uint4 b = {pk[4], pk[5], pk[6], pk[7]};
  *(uint4*)(lbase) = a;
  *(uint4*)(lbase + 8) = b;
}

// ---------- kernel 1: W recurrent half -> f16 MFMA A-fragments ----------
// WF[g][rt][kt][lane] (uint4): 8 f16 = W_g[rt*16+(lane&15)][512 + kt*32 + (lane>>4)*8 + 0..7]
__global__ void k_convert_w(const float* __restrict__ Wr, const float* __restrict__ Wz,
                            const float* __restrict__ Wh, uint4* __restrict__ WF) {
  int g = blockIdx.y;
  const float* Ws = (g == 0) ? Wr : ((g == 1) ? Wz : Wh);
  int i = blockIdx.x * 256 + threadIdx.x;   // 0..32767
  int lane = i & 63;
  int kt   = (i >> 6) & 15;
  int rt   = i >> 10;                       // 0..31
  int row  = rt * 16 + (lane & 15);
  int col  = 512 + kt * 32 + (lane >> 4) * 8;
  const float* src = Ws + (size_t)row * 1024 + col;
  float4 a = *(const float4*)src;
  float4 b = *(const float4*)(src + 4);
  uint4 o;
  o.x = pk2h(a.x, a.y); o.y = pk2h(a.z, a.w);
  o.z = pk2h(b.x, b.y); o.w = pk2h(b.z, b.w);
  WF[((size_t)(g * 32 + rt) * 16 + kt) * 64 + lane] = o;
}

// ---------- kernel 2: projection GEMM (f32 in, bf16 MFMA, f16 out) ----------
__global__ __launch_bounds__(256) void k_proj_gemm(
    const float* __restrict__ x,
    const float* __restrict__ Wr, const float* __restrict__ Wz, const float* __restrict__ Wh,
    const float* __restrict__ br, const float* __restrict__ bz, const float* __restrict__ bh,
    u16* __restrict__ P)
{
  const int g  = blockIdx.z;
  const int bm = blockIdx.x * 64;
  const int bn = blockIdx.y * 64;
  const float* Ws = (g == 0) ? Wr : ((g == 1) ? Wz : Wh);
  __shared__ __align__(16) u16 As[64][32];
  __shared__ __align__(16) u16 Bs[64][32];
  const int tid  = threadIdx.x;
  const int lane = tid & 63;
  const int wm   = (tid >> 6) >> 1;
  const int wn   = (tid >> 6) & 1;
  const int srow = tid >> 2;
  const int scol = (tid & 3) * 8;

  f32x4 zero4 = {0.f, 0.f, 0.f, 0.f};
  f32x4 acc[2][2];
  acc[0][0] = zero4; acc[0][1] = zero4; acc[1][0] = zero4; acc[1][1] = zero4;

  for (int k0 = 0; k0 < 512; k0 += 32) {
    __syncthreads();
    {
      const float* xs = x + (size_t)(bm + srow) * 512 + k0 + scol;
      float4 a = *(const float4*)xs, b = *(const float4*)(xs + 4);
      uint4 av; av.x = pkbf2(a.x, a.y); av.y = pkbf2(a.z, a.w);
      av.z = pkbf2(b.x, b.y); av.w = pkbf2(b.z, b.w);
      *(uint4*)(&As[srow][scol]) = av;
      const float* wsrc = Ws + (size_t)(bn + srow) * 1024 + k0 + scol;
      float4 c = *(const float4*)wsrc, d = *(const float4*)(wsrc + 4);
      uint4 bv; bv.x = pkbf2(c.x, c.y); bv.y = pkbf2(c.z, c.w);
      bv.z = pkbf2(d.x, d.y); bv.w = pkbf2(d.z, d.w);
      *(uint4*)(&Bs[srow][scol]) = bv;
    }
    __syncthreads();
#pragma unroll
    for (int mi = 0; mi < 2; ++mi) {
      bf16x8 a = *(const bf16x8*)(&As[wm * 32 + mi * 16 + (lane & 15)][(lane >> 4) * 8]);
#pragma unroll
      for (int ni = 0; ni < 2; ++ni) {
        bf16x8 b = *(const bf16x8*)(&Bs[wn * 32 + ni * 16 + (lane & 15)][(lane >> 4) * 8]);
        acc[mi][ni] = __builtin_amdgcn_mfma_f32_16x16x32_bf16(a, b, acc[mi][ni], 0, 0, 0);
      }
    }
  }
  const float* bias = (g == 0) ? br : ((g == 1) ? bz : bh);
#pragma unroll
  for (int mi = 0; mi < 2; ++mi)
#pragma unroll
    for (int ni = 0; ni < 2; ++ni) {
      int col  = bn + wn * 32 + ni * 16 + (lane & 15);
      float bv = bias[col];
#pragma unroll
      for (int r = 0; r < 4; ++r) {
        int row = bm + wm * 32 + mi * 16 + (lane >> 4) * 4 + r;
        int bb = row >> 9, ss = row & 511;
        float v = acc[mi][ni][r] + bv;
        P[((size_t)g * 512 + ss) * (64 * 512) + (size_t)bb * 512 + col] =
            __builtin_bit_cast(u16, (_Float16)v);
      }
    }
}

// ---------- kernel 3: GRU scan — 8-block clusters, gate-split waves ----------
// 32 blocks x 512 thr. cluster c = blockIdx>>3 owns batches 16c..16c+15;
// block q = blockIdx&7 owns rows [64q, 64q+64).
//   Waves 0-3: r-gate (W_r frags, 64 VGPR) for row-tile wl = w.
//   Waves 4-7: z-gate (W_z frags, 64 VGPR), same row-tiles.
//   W_h: 2-way k-split, 8 frags (32 VGPR) per wave; partials reduced via LDS.
// Total weight demand 96 VGPR/thread; waves_per_eu(2,2) pins a 256-VGPR budget.
// Exchange (rh, h): round-5 tag-poll (relaxed agent atomics, parity dbuf).
__global__ __attribute__((amdgpu_flat_work_group_size(512, 512),
                          amdgpu_waves_per_eu(2, 2)))
void k_gru_scan(
    const float* __restrict__ h0,
    const u16*  __restrict__ P,       // [3][512 ts][64 b][512 j] f16
    const uint4* __restrict__ WF,     // fragment-packed recurrent W (f16)
    u32* __restrict__ RHX,            // [2 par][4 c][16 b][512 j] tagged r*h
    u32* __restrict__ HX,             // [2 par][4 c][16 b][512 j] tagged h
    float* __restrict__ y,
    float* __restrict__ hlast)
{
  const int q = blockIdx.x & 7;
  const int c = blockIdx.x >> 3;
  const int t = threadIdx.x;
  const int w = t >> 6;              // wave 0..7
  const int l = t & 63;
  const int bq = l & 15;             // batch within cluster (MFMA col)
  const int g4 = l >> 4;             // 0..3
  const int g1 = w >> 2;             // 0: r-wave, 1: z-wave (also W_h k-half)
  const int wl = w & 3;              // row-tile within own 64 rows
  const int rtile = q * 4 + wl;      // global row-tile 0..31
  const int jrow = q * 64 + wl * 16 + g4 * 4;   // own 4 output rows
  const int jloc = wl * 16 + g4 * 4;            // local row index 0..63
  const int bgA = c * 16 + bq;

  __shared__ __align__(16) u16 hbuf[16 * 520];    // f16 h   [b][j], pad 8
  __shared__ __align__(16) u16 rhbuf[16 * 520];   // f16 r*h [b][j], pad 8
  __shared__ float zbuf[64][16];                  // z [local row][b]
  __shared__ __align__(16) f32x4 pLDS[4][64];     // k-half-1 partials

  // --- weights into VGPRs: wa = W_r or W_z (16 frags), whf = W_h k-half (8) ---
  f16x8 wa[16], whf[8];
#pragma unroll
  for (int kt = 0; kt < 16; ++kt)
    wa[kt] = __builtin_bit_cast(f16x8, WF[((size_t)(g1 * 32 + rtile) * 16 + kt) * 64 + l]);
#pragma unroll
  for (int i = 0; i < 8; ++i)
    whf[i] = __builtin_bit_cast(f16x8,
        WF[((size_t)(2 * 32 + rtile) * 16 + (g1 * 8 + i)) * 64 + l]);
#pragma unroll
  for (int kt = 0; kt < 16; ++kt)
    asm volatile("" : "+v"(wa[kt]));
#pragma unroll
  for (int i = 0; i < 8; ++i)
    asm volatile("" : "+v"(whf[i]));

  // --- init h: hreg (waves 0-3, own rows f32) + hbuf (f16, all rows) ---
  f32x4 hreg = *(const f32x4*)(h0 + (size_t)bgA * 512 + jrow);
  {
    int b = t >> 5, j = (t & 31) * 16;
    const float4* s = (const float4*)(h0 + (size_t)(c * 16 + b) * 512 + j);
    float4 v0 = s[0], v1 = s[1], v2 = s[2], v3 = s[3];
    uint4 o0, o1;
    o0.x = pk2h(v0.x, v0.y); o0.y = pk2h(v0.z, v0.w);
    o0.z = pk2h(v1.x, v1.y); o0.w = pk2h(v1.z, v1.w);
    o1.x = pk2h(v2.x, v2.y); o1.y = pk2h(v2.z, v2.w);
    o1.z = pk2h(v3.x, v3.y); o1.w = pk2h(v3.z, v3.w);
    uint4* d = (uint4*)&hbuf[b * 520 + j];
    d[0] = o0; d[1] = o1;
  }
  __syncthreads();

  const u16* Pg  = P + (size_t)g1 * PJ_GATE + (size_t)bgA * 512 + jrow;  // own gate
  const u16* Pph = P + 2 * PJ_GATE + (size_t)bgA * 512 + jrow;

  // poll mapping: b = t>>5, j = (t&31)*16, 8 u64 contiguous
  const int bR = t >> 5;
  const int jR = (t & 31) * 16;
  const int CL  = 16 * 512;               // u32 per cluster
  const int PAR = 4 * CL;                 // u32 per parity

  uint2 pgu = *(const uint2*)Pg;

  for (int ts = 0; ts < S_; ++ts) {
    const int par = ts & 1;
    const u32 taghi = (u32)(ts + 1) << 16;
    const u64 tp = (u64)taghi | ((u64)taghi << 32);
    u32* RHXp = RHX + par * PAR + c * CL;
    u32* HXp  = HX  + par * PAR + c * CL;

    // prefetch P_h for combine (waves 0-3 only)
    uint2 phu = {0, 0};
    if (g1 == 0) phu = *(const uint2*)(Pph + (size_t)ts * 32768);

    // ---- phase A: own gate GEMV over full k (16 MFMAs) ----
    f32x4 aa = {0.f, 0.f, 0.f, 0.f};
#pragma unroll
    for (int kt = 0; kt < 16; ++kt) {
      f16x8 hv = *(const f16x8*)&hbuf[bq * 520 + g4 * 8 + kt * 32];
      aa = __builtin_amdgcn_mfma_f32_16x16x32_f16(wa[kt], hv, aa, 0, 0, 0);
    }
    h2_t pg0 = __builtin_bit_cast(h2_t, pgu.x), pg1 = __builtin_bit_cast(h2_t, pgu.y);
    float v0 = sigmoidf_(aa[0] + (float)pg0[0]);
    float v1 = sigmoidf_(aa[1] + (float)pg0[1]);
    float v2 = sigmoidf_(aa[2] + (float)pg1[0]);
    float v3 = sigmoidf_(aa[3] + (float)pg1[1]);
    if (g1 == 0) {
      f32x4 rh = {v0 * hreg[0], v1 * hreg[1], v2 * hreg[2], v3 * hreg[3]};
      pub4(RHXp + bq * 512 + jrow, taghi, rh);
    } else {
      zbuf[jloc + 0][bq] = v0;
      zbuf[jloc + 1][bq] = v1;
      zbuf[jloc + 2][bq] = v2;
      zbuf[jloc + 3][bq] = v3;
    }
    // prefetch next step's own-gate P (overlaps poll)
    {
      int tsn = (ts < S_ - 1) ? ts + 1 : ts;
      pgu = *(const uint2*)(Pg + (size_t)tsn * 32768);
    }

    // ---- poll rh (all 512 rows x own batch slice) -> rhbuf ----
    poll8_to_lds(RHXp + bR * 512 + jR, &rhbuf[bR * 520 + jR], tp);
    __syncthreads();   // rhbuf + zbuf ready

    // ---- phase B: htilde partials, own rows, k-half = g1 (8 MFMAs) ----
    f32x4 pb = {0.f, 0.f, 0.f, 0.f};
#pragma unroll
    for (int i = 0; i < 8; ++i) {
      int kt = g1 * 8 + i;
      f16x8 rv = *(const f16x8*)&rhbuf[bq * 520 + g4 * 8 + kt * 32];
      pb = __builtin_amdgcn_mfma_f32_16x16x32_f16(whf[i], rv, pb, 0, 0, 0);
    }
    if (g1 == 1) pLDS[wl][l] = pb;
    __syncthreads();   // partials staged

    // ---- combine (waves 0-3): reduce, tanh, gate, update h, publish ----
    if (g1 == 0) {
      f32x4 s = pb + pLDS[wl][l];
      h2_t ph0 = __builtin_bit_cast(h2_t, phu.x), ph1 = __builtin_bit_cast(h2_t, phu.y);
      float ht0 = tanhf_(s[0] + (float)ph0[0]);
      float ht1 = tanhf_(s[1] + (float)ph0[1]);
      float ht2 = tanhf_(s[2] + (float)ph1[0]);
      float ht3 = tanhf_(s[3] + (float)ph1[1]);
      float z0 = zbuf[jloc + 0][bq], z1 = zbuf[jloc + 1][bq];
      float z2 = zbuf[jloc + 2][bq], z3 = zbuf[jloc + 3][bq];
      f32x4 hn;
      hn[0] = z0 * ht0 + (1.f - z0) * hreg[0];
      hn[1] = z1 * ht1 + (1.f - z1) * hreg[1];
      hn[2] = z2 * ht2 + (1.f - z2) * hreg[2];
      hn[3] = z3 * ht3 + (1.f - z3) * hreg[3];
      hreg = hn;
      pub4(HXp + bq * 512 + jrow, taghi, hn);
      __builtin_nontemporal_store(hn,
          (f32x4*)(y + ((size_t)bgA * 512 + ts) * 512 + jrow));
    }

    // ---- poll h -> hbuf (all threads) ----
    poll8_to_lds(HXp + bR * 512 + jR, &hbuf[bR * 520 + jR], tp);
    __syncthreads();   // hbuf ready for next phase A
  }

  if (g1 == 0)
    *(f32x4*)(hlast + (size_t)bgA * 512 + jrow) = hreg;
}

// ---------- host ----------
extern "C" void kernel_launch(void* const* d_in, const int* in_sizes, int n_in,
                              void* d_out, int out_size, void* d_ws, size_t ws_size,
                              hipStream_t stream) {
  const float* x  = (const float*)d_in[0];
  const float* h0 = (const float*)d_in[1];
  const float* Wr = (const float*)d_in[2];
  const float* br = (const float*)d_in[3];
  const float* Wz = (const float*)d_in[4];
  const float* bz = (const float*)d_in[5];
  const float* Wh = (const float*)d_in[6];
  const float* bh = (const float*)d_in[7];

  char* ws = (char*)d_ws;
  // layout: WF 1.5MB @0 | P 96MB @2MB | RHX 256KB | HX 256KB
  uint4* WF  = (uint4*)ws;
  u16*   P   = (u16*)(ws + 2097152);
  u32*   RHX = (u32*)(ws + 102760448);
  u32*   HX  = (u32*)(ws + 103022592);

  float* y     = (float*)d_out;
  float* hlast = y + (size_t)B_ * S_ * H_;

  (void)hipMemsetAsync(ws + 102760448, 0, 524288, stream);   // clear exchange tags
  k_convert_w<<<dim3(128, 3), dim3(256), 0, stream>>>(Wr, Wz, Wh, WF);
  k_proj_gemm<<<dim3(512, 8, 3), dim3(256), 0, stream>>>(x, Wr, Wz, Wh, br, bz, bh, P);
  k_gru_scan<<<dim3(32), dim3(512), 0, stream>>>(h0, P, WF, RHX, HX, y, hlast);
}